// Round 3
// baseline (199.659 us; speedup 1.0000x reference)
//
#include <hip/hip_runtime.h>

#define EPSV 1e-5f

// Workspace layout (floats):
//   kbufT @ 0      : [b][g][l][c]  8*4*49*8 = 12544
//   pw1T  @ 12544  : [l][o<25 pad32] 49*32  = 1568
//   pw2T  @ 14112  : [l][o<49 pad64] 49*64  = 3136
//   wqT   @ 17248  : [i][o] 32*32          = 1024
//   dyT   @ 18272  : [i][o] 64*64          = 4096
#define OFF_PW1T 12544
#define OFF_PW2T 14112
#define OFF_WQT  17248
#define OFF_DYT  18272

// ---------------------------------------------------------------------------
// Prep kernel: transpose weights so the main kernel's uniform (scalar) loads
// are contiguous rows -> s_load_dwordx8/x16.
// ---------------------------------------------------------------------------
__global__ __launch_bounds__(512) void prep_weights(
    const float* __restrict__ wq_w, const float* __restrict__ proj_w,
    const float* __restrict__ dy_w, float* __restrict__ ws)
{
  const int t = blockIdx.x * 512 + threadIdx.x;  // 8192 threads total
  float* wqT  = ws + OFF_WQT;
  float* pw1T = ws + OFF_PW1T;
  float* pw2T = ws + OFF_PW2T;
  float* dyT  = ws + OFF_DYT;
  for (int idx = t; idx < 1024; idx += 8192) {
    const int i = idx >> 5, o = idx & 31;
    wqT[idx] = wq_w[o * 32 + i];
  }
  for (int idx = t; idx < 1568; idx += 8192) {
    const int l = idx >> 5, o = idx & 31;
    pw1T[idx] = (o < 25) ? proj_w[o * 49 + l] : 0.f;
  }
  for (int idx = t; idx < 3136; idx += 8192) {
    const int l = idx >> 6, o = idx & 63;
    pw2T[idx] = (o < 49) ? proj_w[(25 + o) * 49 + l] : 0.f;
  }
  for (int idx = t; idx < 4096; idx += 8192) {
    const int i = idx >> 6, o = idx & 63;
    dyT[idx] = dy_w[o * 64 + i];
  }
}

// ---------------------------------------------------------------------------
// Kernel 1: pool kctx (channels 32..63) to 7x7, apply wk conv1x1 + BN.
// Output kbufT layout: [b][g][l=p*7+q][c] (c contiguous for x8 scalar loads).
// ---------------------------------------------------------------------------
__global__ __launch_bounds__(256) void pool_k_kernel(
    const float* __restrict__ x,
    const float* __restrict__ wk_w, const float* __restrict__ wk_g,
    const float* __restrict__ wk_b, const float* __restrict__ wk_m,
    const float* __restrict__ wk_v, float* __restrict__ kbufT)
{
  const int b = blockIdx.x / 7;
  const int p = blockIdx.x % 7;
  const int tid = threadIdx.x;
  __shared__ float s_tmp[32 * 64];  // row-pooled [c][w]
  __shared__ float s_kp[32 * 7];    // fully pooled [c][q]

  const int sh = (p * 64) / 7, eh = ((p + 1) * 64 + 6) / 7;
  const float invH = 1.0f / (float)(eh - sh);
  for (int idx = tid; idx < 2048; idx += 256) {
    const int c = idx >> 6, ww = idx & 63;
    const float* xp = x + ((size_t)(b * 64 + 32 + c)) * 4096 + ww;
    float s = 0.f;
    for (int hh = sh; hh < eh; ++hh) s += xp[hh * 64];
    s_tmp[idx] = s * invH;
  }
  __syncthreads();
  if (tid < 224) {
    const int c = tid / 7, q = tid % 7;
    const int sw = (q * 64) / 7, ew = ((q + 1) * 64 + 6) / 7;
    float s = 0.f;
    for (int ww = sw; ww < ew; ++ww) s += s_tmp[c * 64 + ww];
    s_kp[c * 7 + q] = s / (float)(ew - sw);
  }
  __syncthreads();
  if (tid < 224) {
    const int o = tid / 7, q = tid % 7;
    float s = 0.f;
#pragma unroll
    for (int i = 0; i < 32; i++) s += wk_w[o * 32 + i] * s_kp[i * 7 + q];
    const float sc = wk_g[o] * rsqrtf(wk_v[o] + EPSV);
    const int g = o >> 3, c = o & 7, l = p * 7 + q;
    kbufT[(((size_t)b * 4 + g) * 49 + l) * 8 + c] =
        (s - wk_m[o]) * sc + wk_b[o];
  }
}

// ---------------------------------------------------------------------------
// Kernel 2: fused main. Block = 512 threads = 2 branches x 4 heads x 64 cols,
// one image row per block. proj is l-outer / o-inner: wv[l] computed on the
// fly (no wv[] array -> no spills), scattered into 25/49 accumulators with
// contiguous scalar-weight rows from the transposed tables.
// ---------------------------------------------------------------------------
__global__ __launch_bounds__(512, 2) void contmix_main(
    const float* __restrict__ x,
    const float* __restrict__ wq_g, const float* __restrict__ wq_b,
    const float* __restrict__ wq_m, const float* __restrict__ wq_v,
    const float* __restrict__ proj_b,
    const float* __restrict__ rpb1, const float* __restrict__ rpb2,
    const float* __restrict__ dy_g, const float* __restrict__ dy_b,
    const float* __restrict__ dy_m, const float* __restrict__ dy_v,
    const float* __restrict__ ws,
    float* __restrict__ out)
{
  __shared__ float s_rpb1[4 * 81];
  __shared__ float s_rpb2[4 * 169];
  __shared__ float s_val[64 * 64];  // row result [ch][w] pre-final-conv

  const int bx = blockIdx.x;
  const int b = bx >> 6;
  const int h = bx & 63;
  const int tid = threadIdx.x;
  const int w = tid & 63;
  const int bru = __builtin_amdgcn_readfirstlane(tid >> 8);
  const int gu  = __builtin_amdgcn_readfirstlane((tid >> 6) & 3);

  for (int i = tid; i < 324; i += 512) s_rpb1[i] = rpb1[i];
  for (int i = tid; i < 676; i += 512) s_rpb2[i] = rpb2[i];
  __syncthreads();

  const float* xb = x + (size_t)b * 64 * 4096;

  // ---- q = BN(wq @ x[0:32]) * SCALE : 8 channels of this head ----
  float q8[8];
#pragma unroll
  for (int o = 0; o < 8; o++) q8[o] = 0.f;
  {
    const float* wqt = ws + OFF_WQT + gu * 8;  // row i: 8 contiguous floats
#pragma unroll
    for (int i = 0; i < 32; i++) {
      const float xv = xb[i * 4096 + h * 64 + w];
#pragma unroll
      for (int o = 0; o < 8; o++) q8[o] += wqt[i * 32 + o] * xv;
    }
#pragma unroll
    for (int o = 0; o < 8; o++) {
      const int oc = gu * 8 + o;
      const float s = wq_g[oc] * rsqrtf(wq_v[oc] + EPSV);
      q8[o] = (q8[o] * s + (wq_b[oc] - wq_m[oc] * s)) * 0.25f;
    }
  }

  const float* kt = ws + ((size_t)b * 4 + gu) * 392;  // [l][c] rows of 8

  // ---- relative-position-bias bases (reference uses reversed pixel) ----
  const int ph = 63 - h, pw = 63 - w;

  if (bru == 0) {
    // ================= attn1 branch (5x5 = 25) =================
    const int bih5 = ph - min(max(ph - 2, 0), 59);
    const int biw5 = pw - min(max(pw - 2, 0), 59);
    const int si5 = min(max(h - 2, 0), 59), sj5 = min(max(w - 2, 0), 59);
    float l1[25];
#pragma unroll
    for (int o = 0; o < 25; o++) l1[o] = proj_b[o];
    const float* p1 = ws + OFF_PW1T;
#pragma unroll 4
    for (int l = 0; l < 49; l++) {
      float a = 0.f;
#pragma unroll
      for (int c = 0; c < 8; c++) a += q8[c] * kt[l * 8 + c];
      const float* pr = p1 + l * 32;
#pragma unroll
      for (int o = 0; o < 25; o++) l1[o] += pr[o] * a;
    }
    const float* rp1 = s_rpb1 + gu * 81 + bih5 * 9 + biw5;
#pragma unroll
    for (int ki = 0; ki < 5; ki++)
#pragma unroll
      for (int kj = 0; kj < 5; kj++) l1[ki * 5 + kj] += rp1[ki * 9 + kj];

    float mx = l1[0];
#pragma unroll
    for (int o = 1; o < 25; o++) mx = fmaxf(mx, l1[o]);
    float sum = 0.f;
#pragma unroll
    for (int o = 0; o < 25; o++) {
      const float e = __expf(l1[o] - mx);
      l1[o] = e;
      sum += e;
    }
    const float inv = 1.f / sum;

    float acc[8];
#pragma unroll
    for (int c = 0; c < 8; c++) acc[c] = 0.f;
    const float* vb = xb + gu * 8 * 4096;
#pragma unroll
    for (int i = 0; i < 5; i++) {
      const float* vr = vb + (si5 + i) * 64 + sj5;
#pragma unroll
      for (int j = 0; j < 5; j++) {
        const float a = l1[i * 5 + j];
#pragma unroll
        for (int c = 0; c < 8; c++) acc[c] += a * vr[c * 4096 + j];
      }
    }
#pragma unroll
    for (int c = 0; c < 8; c++) s_val[(gu * 8 + c) * 64 + w] = acc[c] * inv;
  } else {
    // ================= attn2 branch (7x7 = 49) =================
    const int bih7 = ph - min(max(ph - 3, 0), 57);
    const int biw7 = pw - min(max(pw - 3, 0), 57);
    const int si7 = min(max(h - 3, 0), 57), sj7 = min(max(w - 3, 0), 57);
    float l2[49];
#pragma unroll
    for (int o = 0; o < 49; o++) l2[o] = proj_b[25 + o];
    const float* p2 = ws + OFF_PW2T;
#pragma unroll 4
    for (int l = 0; l < 49; l++) {
      float a = 0.f;
#pragma unroll
      for (int c = 0; c < 8; c++) a += q8[c] * kt[l * 8 + c];
      const float* pr = p2 + l * 64;
#pragma unroll
      for (int o = 0; o < 49; o++) l2[o] += pr[o] * a;
    }
    const float* rp2 = s_rpb2 + gu * 169 + bih7 * 13 + biw7;
#pragma unroll
    for (int ki = 0; ki < 7; ki++)
#pragma unroll
      for (int kj = 0; kj < 7; kj++) l2[ki * 7 + kj] += rp2[ki * 13 + kj];

    float mx = l2[0];
#pragma unroll
    for (int o = 1; o < 49; o++) mx = fmaxf(mx, l2[o]);
    float sum = 0.f;
#pragma unroll
    for (int o = 0; o < 49; o++) {
      const float e = __expf(l2[o] - mx);
      l2[o] = e;
      sum += e;
    }
    const float inv = 1.f / sum;

    float acc[8];
#pragma unroll
    for (int c = 0; c < 8; c++) acc[c] = 0.f;
    const float* vb = xb + (32 + gu * 8) * 4096;
#pragma unroll
    for (int i = 0; i < 7; i++) {
      const float* vr = vb + (si7 + i) * 64 + sj7;
#pragma unroll
      for (int j = 0; j < 7; j++) {
        const float a = l2[i * 7 + j];
#pragma unroll
        for (int c = 0; c < 8; c++) acc[c] += a * vr[c * 4096 + j];
      }
    }
#pragma unroll
    for (int c = 0; c < 8; c++) s_val[(32 + gu * 8 + c) * 64 + w] = acc[c] * inv;
  }

  __syncthreads();

  // ================= fused final conv1x1 (64->64) + BN =================
  // 512 threads = 8 out-channel groups of 8 x 64 cols.
  {
    const int ogu = __builtin_amdgcn_readfirstlane(tid >> 6);  // 0..7
    float facc[8];
#pragma unroll
    for (int oo = 0; oo < 8; oo++) facc[oo] = 0.f;
    const float* dyt = ws + OFF_DYT + ogu * 8;  // row i: 8 contiguous floats
#pragma unroll
    for (int i = 0; i < 64; i++) {
      const float v = s_val[i * 64 + w];
#pragma unroll
      for (int oo = 0; oo < 8; oo++) facc[oo] += dyt[i * 64 + oo] * v;
    }
#pragma unroll
    for (int oo = 0; oo < 8; oo++) {
      const int oc = ogu * 8 + oo;
      const float sc = dy_g[oc] * rsqrtf(dy_v[oc] + EPSV);
      out[((size_t)(b * 64 + oc)) * 4096 + h * 64 + w] =
          (facc[oo] - dy_m[oc]) * sc + dy_b[oc];
    }
  }
}

// ---------------------------------------------------------------------------
extern "C" void kernel_launch(void* const* d_in, const int* in_sizes, int n_in,
                              void* d_out, int out_size, void* d_ws, size_t ws_size,
                              hipStream_t stream)
{
  const float* x      = (const float*)d_in[0];
  const float* wq_w   = (const float*)d_in[1];
  const float* wq_g   = (const float*)d_in[2];
  const float* wq_b   = (const float*)d_in[3];
  const float* wq_m   = (const float*)d_in[4];
  const float* wq_v   = (const float*)d_in[5];
  const float* wk_w   = (const float*)d_in[6];
  const float* wk_g   = (const float*)d_in[7];
  const float* wk_b   = (const float*)d_in[8];
  const float* wk_m   = (const float*)d_in[9];
  const float* wk_v   = (const float*)d_in[10];
  const float* proj_w = (const float*)d_in[11];
  const float* proj_b = (const float*)d_in[12];
  const float* rpb1   = (const float*)d_in[13];
  const float* rpb2   = (const float*)d_in[14];
  const float* dy_w   = (const float*)d_in[15];
  const float* dy_g   = (const float*)d_in[16];
  const float* dy_b   = (const float*)d_in[17];
  const float* dy_m   = (const float*)d_in[18];
  const float* dy_v   = (const float*)d_in[19];

  float* ws = (float*)d_ws;

  prep_weights<<<16, 512, 0, stream>>>(wq_w, proj_w, dy_w, ws);
  pool_k_kernel<<<56, 256, 0, stream>>>(x, wk_w, wk_g, wk_b, wk_m, wk_v, ws);
  contmix_main<<<512, 512, 0, stream>>>(x, wq_g, wq_b, wq_m, wq_v,
                                        proj_b, rpb1, rpb2,
                                        dy_g, dy_b, dy_m, dy_v,
                                        ws, (float*)d_out);
}

// Round 4
// 165.944 us; speedup vs baseline: 1.2032x; 1.2032x over previous
//
#include <hip/hip_runtime.h>

#define EPSV 1e-5f

// Workspace layout (floats):
//   kbuf @ 0     : [b][g][c][l]  8*4*8*49 = 12544
//   W    @ 12544 : [b][g][o<74][c<8]      = 18944   (W = proj_w @ k^T)
//   wqT  @ 31488 : [i][o] 32*32           = 1024
//   dyT  @ 32512 : [i][o] 64*64           = 4096
#define OFF_W    12544
#define OFF_WQT  31488
#define OFF_DYT  32512

typedef float f4u __attribute__((ext_vector_type(4), aligned(4)));

// ---------------------------------------------------------------------------
__global__ __launch_bounds__(512) void prep_weights(
    const float* __restrict__ wq_w, const float* __restrict__ dy_w,
    float* __restrict__ ws)
{
  const int t = blockIdx.x * 512 + threadIdx.x;  // 5120 threads
  float* wqT = ws + OFF_WQT;
  float* dyT = ws + OFF_DYT;
  if (t < 1024) {
    const int i = t >> 5, o = t & 31;
    wqT[t] = wq_w[o * 32 + i];
  }
  const int t2 = t - 1024;
  if (t2 >= 0 && t2 < 4096) {
    const int i = t2 >> 6, o = t2 & 63;
    dyT[t2] = dy_w[o * 64 + i];
  }
}

// ---------------------------------------------------------------------------
// pool kctx (ch 32..63) to 7x7, wk conv1x1 + BN. kbuf: [b][g][c][l] l-contig.
// ---------------------------------------------------------------------------
__global__ __launch_bounds__(256) void pool_k_kernel(
    const float* __restrict__ x,
    const float* __restrict__ wk_w, const float* __restrict__ wk_g,
    const float* __restrict__ wk_b, const float* __restrict__ wk_m,
    const float* __restrict__ wk_v, float* __restrict__ kbuf)
{
  const int b = blockIdx.x / 7;
  const int p = blockIdx.x % 7;
  const int tid = threadIdx.x;
  __shared__ float s_tmp[32 * 64];
  __shared__ float s_kp[32 * 7];

  const int sh = (p * 64) / 7, eh = ((p + 1) * 64 + 6) / 7;
  const float invH = 1.0f / (float)(eh - sh);
  for (int idx = tid; idx < 2048; idx += 256) {
    const int c = idx >> 6, ww = idx & 63;
    const float* xp = x + ((size_t)(b * 64 + 32 + c)) * 4096 + ww;
    float s = 0.f;
    for (int hh = sh; hh < eh; ++hh) s += xp[hh * 64];
    s_tmp[idx] = s * invH;
  }
  __syncthreads();
  if (tid < 224) {
    const int c = tid / 7, q = tid % 7;
    const int sw = (q * 64) / 7, ew = ((q + 1) * 64 + 6) / 7;
    float s = 0.f;
    for (int ww = sw; ww < ew; ++ww) s += s_tmp[c * 64 + ww];
    s_kp[c * 7 + q] = s / (float)(ew - sw);
  }
  __syncthreads();
  if (tid < 224) {
    const int o = tid / 7, q = tid % 7;
    float s = 0.f;
#pragma unroll
    for (int i = 0; i < 32; i++) s += wk_w[o * 32 + i] * s_kp[i * 7 + q];
    const float sc = wk_g[o] * rsqrtf(wk_v[o] + EPSV);
    const int g = o >> 3, c = o & 7, l = p * 7 + q;
    kbuf[(((size_t)b * 4 + g) * 8 + c) * 49 + l] =
        (s - wk_m[o]) * sc + wk_b[o];
  }
}

// ---------------------------------------------------------------------------
// W[bg][o][c] = sum_l proj_w[o][l] * k[bg][c][l].  32 blocks, 256 threads.
// ---------------------------------------------------------------------------
__global__ __launch_bounds__(256) void fold_w_kernel(
    const float* __restrict__ proj_w, const float* __restrict__ ws_in,
    float* __restrict__ Wout)
{
  const int bg = blockIdx.x;
  const int tid = threadIdx.x;
  __shared__ float s_k[392];
  for (int i = tid; i < 392; i += 256) s_k[i] = ws_in[(size_t)bg * 392 + i];
  __syncthreads();
  for (int idx = tid; idx < 592; idx += 256) {
    const int o = idx >> 3, c = idx & 7;
    float s = 0.f;
#pragma unroll
    for (int l = 0; l < 49; l++) s += proj_w[o * 49 + l] * s_k[c * 49 + l];
    Wout[(size_t)bg * 592 + idx] = s;
  }
}

// ---------------------------------------------------------------------------
// Fused main. Block = 512 = 2 branches x 4 heads x 64 cols, one row.
// Proj uses folded W: logits[o] = proj_b[o] + sum_c W[o][c]*q8[c].
// ---------------------------------------------------------------------------
__global__ __launch_bounds__(512, 3) void contmix_main(
    const float* __restrict__ x,
    const float* __restrict__ wq_g, const float* __restrict__ wq_b,
    const float* __restrict__ wq_m, const float* __restrict__ wq_v,
    const float* __restrict__ proj_b,
    const float* __restrict__ rpb1, const float* __restrict__ rpb2,
    const float* __restrict__ dy_g, const float* __restrict__ dy_b,
    const float* __restrict__ dy_m, const float* __restrict__ dy_v,
    const float* __restrict__ ws,
    float* __restrict__ out)
{
  __shared__ float s_rpb1[4 * 81];
  __shared__ float s_rpb2[4 * 169];
  __shared__ float s_val[64 * 64];  // [ch][w]

  const int bx = blockIdx.x;
  const int b = bx >> 6;
  const int h = bx & 63;
  const int tid = threadIdx.x;
  const int w = tid & 63;
  const int bru = __builtin_amdgcn_readfirstlane(tid >> 8);
  const int gu  = __builtin_amdgcn_readfirstlane((tid >> 6) & 3);

  for (int i = tid; i < 324; i += 512) s_rpb1[i] = rpb1[i];
  for (int i = tid; i < 676; i += 512) s_rpb2[i] = rpb2[i];
  __syncthreads();

  const float* xb = x + (size_t)b * 64 * 4096;

  // ---- q = BN(wq @ x[0:32]) * SCALE ----
  float q8[8];
#pragma unroll
  for (int o = 0; o < 8; o++) q8[o] = 0.f;
  {
    const float* wqt = ws + OFF_WQT + gu * 8;
#pragma unroll
    for (int i = 0; i < 32; i++) {
      const float xv = xb[i * 4096 + h * 64 + w];
#pragma unroll
      for (int o = 0; o < 8; o++) q8[o] += wqt[i * 32 + o] * xv;
    }
#pragma unroll
    for (int o = 0; o < 8; o++) {
      const int oc = gu * 8 + o;
      const float s = wq_g[oc] * rsqrtf(wq_v[oc] + EPSV);
      q8[o] = (q8[o] * s + (wq_b[oc] - wq_m[oc] * s)) * 0.25f;
    }
  }

  const float* Wr = ws + OFF_W + (size_t)(b * 4 + gu) * 592;  // uniform

  const int ph = 63 - h, pw = 63 - w;

  if (bru == 0) {
    // ===== attn1 (5x5) =====
    const int bih5 = ph - min(max(ph - 2, 0), 59);
    const int biw5 = pw - min(max(pw - 2, 0), 59);
    const int si5 = min(max(h - 2, 0), 59), sj5 = min(max(w - 2, 0), 59);
    float l1[25];
#pragma unroll
    for (int o = 0; o < 25; o++) {
      const float* wo = Wr + o * 8;
      float s = proj_b[o];
#pragma unroll
      for (int c = 0; c < 8; c++) s += wo[c] * q8[c];
      l1[o] = s;
    }
    const float* rp1 = s_rpb1 + gu * 81 + bih5 * 9 + biw5;
#pragma unroll
    for (int ki = 0; ki < 5; ki++)
#pragma unroll
      for (int kj = 0; kj < 5; kj++) l1[ki * 5 + kj] += rp1[ki * 9 + kj];

    float mx = l1[0];
#pragma unroll
    for (int o = 1; o < 25; o++) mx = fmaxf(mx, l1[o]);
    float sum = 0.f;
#pragma unroll
    for (int o = 0; o < 25; o++) {
      const float e = __expf(l1[o] - mx);
      l1[o] = e;
      sum += e;
    }
    const float inv = 1.f / sum;

    float acc[8];
#pragma unroll
    for (int c = 0; c < 8; c++) acc[c] = 0.f;
    const float* vb = xb + gu * 8 * 4096;
#pragma unroll
    for (int i = 0; i < 5; i++) {
      const float a0 = l1[i * 5 + 0], a1 = l1[i * 5 + 1], a2 = l1[i * 5 + 2];
      const float a3 = l1[i * 5 + 3], a4 = l1[i * 5 + 4];
      const float* vr0 = vb + (si5 + i) * 64 + sj5;
#pragma unroll
      for (int c = 0; c < 8; c++) {
        const float* vr = vr0 + c * 4096;
        const f4u f = *(const f4u*)vr;
        const float v4 = vr[4];
        acc[c] += a0 * f.x + a1 * f.y + a2 * f.z + a3 * f.w + a4 * v4;
      }
    }
#pragma unroll
    for (int c = 0; c < 8; c++) s_val[(gu * 8 + c) * 64 + w] = acc[c] * inv;
  } else {
    // ===== attn2 (7x7) =====
    const int bih7 = ph - min(max(ph - 3, 0), 57);
    const int biw7 = pw - min(max(pw - 3, 0), 57);
    const int si7 = min(max(h - 3, 0), 57), sj7 = min(max(w - 3, 0), 57);
    float l2[49];
#pragma unroll
    for (int o = 0; o < 49; o++) {
      const float* wo = Wr + (25 + o) * 8;
      float s = proj_b[25 + o];
#pragma unroll
      for (int c = 0; c < 8; c++) s += wo[c] * q8[c];
      l2[o] = s;
    }
    const float* rp2 = s_rpb2 + gu * 169 + bih7 * 13 + biw7;
#pragma unroll
    for (int ki = 0; ki < 7; ki++)
#pragma unroll
      for (int kj = 0; kj < 7; kj++) l2[ki * 7 + kj] += rp2[ki * 13 + kj];

    float mx = l2[0];
#pragma unroll
    for (int o = 1; o < 49; o++) mx = fmaxf(mx, l2[o]);
    float sum = 0.f;
#pragma unroll
    for (int o = 0; o < 49; o++) {
      const float e = __expf(l2[o] - mx);
      l2[o] = e;
      sum += e;
    }
    const float inv = 1.f / sum;

    float acc[8];
#pragma unroll
    for (int c = 0; c < 8; c++) acc[c] = 0.f;
    const float* vb = xb + (32 + gu * 8) * 4096;
#pragma unroll
    for (int i = 0; i < 7; i++) {
      const float a0 = l2[i * 7 + 0], a1 = l2[i * 7 + 1], a2 = l2[i * 7 + 2];
      const float a3 = l2[i * 7 + 3], a4 = l2[i * 7 + 4], a5 = l2[i * 7 + 5];
      const float a6 = l2[i * 7 + 6];
      const float* vr0 = vb + (si7 + i) * 64 + sj7;
#pragma unroll
      for (int c = 0; c < 8; c++) {
        const float* vr = vr0 + c * 4096;
        const f4u fa = *(const f4u*)vr;        // j 0..3
        const f4u fb = *(const f4u*)(vr + 3);  // j 3..6
        acc[c] += a0 * fa.x + a1 * fa.y + a2 * fa.z + a3 * fa.w +
                  a4 * fb.y + a5 * fb.z + a6 * fb.w;
      }
    }
#pragma unroll
    for (int c = 0; c < 8; c++) s_val[(32 + gu * 8 + c) * 64 + w] = acc[c] * inv;
  }

  __syncthreads();

  // ===== fused final conv1x1 (64->64) + BN =====
  {
    const int ogu = __builtin_amdgcn_readfirstlane(tid >> 6);  // 0..7
    float facc[8];
#pragma unroll
    for (int oo = 0; oo < 8; oo++) facc[oo] = 0.f;
    const float* dyt = ws + OFF_DYT + ogu * 8;
#pragma unroll
    for (int i = 0; i < 64; i++) {
      const float v = s_val[i * 64 + w];
#pragma unroll
      for (int oo = 0; oo < 8; oo++) facc[oo] += dyt[i * 64 + oo] * v;
    }
#pragma unroll
    for (int oo = 0; oo < 8; oo++) {
      const int oc = ogu * 8 + oo;
      const float sc = dy_g[oc] * rsqrtf(dy_v[oc] + EPSV);
      out[((size_t)(b * 64 + oc)) * 4096 + h * 64 + w] =
          (facc[oo] - dy_m[oc]) * sc + dy_b[oc];
    }
  }
}

// ---------------------------------------------------------------------------
extern "C" void kernel_launch(void* const* d_in, const int* in_sizes, int n_in,
                              void* d_out, int out_size, void* d_ws, size_t ws_size,
                              hipStream_t stream)
{
  const float* x      = (const float*)d_in[0];
  const float* wq_w   = (const float*)d_in[1];
  const float* wq_g   = (const float*)d_in[2];
  const float* wq_b   = (const float*)d_in[3];
  const float* wq_m   = (const float*)d_in[4];
  const float* wq_v   = (const float*)d_in[5];
  const float* wk_w   = (const float*)d_in[6];
  const float* wk_g   = (const float*)d_in[7];
  const float* wk_b   = (const float*)d_in[8];
  const float* wk_m   = (const float*)d_in[9];
  const float* wk_v   = (const float*)d_in[10];
  const float* proj_w = (const float*)d_in[11];
  const float* proj_b = (const float*)d_in[12];
  const float* rpb1   = (const float*)d_in[13];
  const float* rpb2   = (const float*)d_in[14];
  const float* dy_w   = (const float*)d_in[15];
  const float* dy_g   = (const float*)d_in[16];
  const float* dy_b   = (const float*)d_in[17];
  const float* dy_m   = (const float*)d_in[18];
  const float* dy_v   = (const float*)d_in[19];

  float* ws = (float*)d_ws;

  prep_weights<<<10, 512, 0, stream>>>(wq_w, dy_w, ws);
  pool_k_kernel<<<56, 256, 0, stream>>>(x, wk_w, wk_g, wk_b, wk_m, wk_v, ws);
  fold_w_kernel<<<32, 256, 0, stream>>>(proj_w, ws, ws + OFF_W);
  contmix_main<<<512, 512, 0, stream>>>(x, wq_g, wq_b, wq_m, wq_v,
                                        proj_b, rpb1, rpb2,
                                        dy_g, dy_b, dy_m, dy_v,
                                        ws, (float*)d_out);
}